// Round 8
// baseline (283.709 us; speedup 1.0000x reference)
//
#include <hip/hip_runtime.h>
#include <math.h>

// N nodes (50000), E edges (600000), D=128.
// R2: f32 atomics hit TCC atomic ceiling -> counting-sort + per-node agg.
// R3: fp32 VALU GEMMs -> split-bf16 MFMA (C = xh*wh + xl*wh + xh*wl).
// R4: K/V 16-bit (halved gather bytes, 25.6 MB working set).
// R5: KV-interleaved loads, ds_swizzle reduce, masked full-width batches.
// R6: single-block scan = 103 us latency chain -> reverted to 3-kernel scan.
// R7: node_agg VALU-issue-bound (96% VALUBusy, 30 slots/edge) ->
//     half-wave per edge + f16 packed v_dot2 (no unpacks, 5-round butterfly
//     shared by 2 edges, sigmoid redundancy halved): ~17 slots/edge.

#define BM 64

typedef __attribute__((ext_vector_type(8))) short bfrag;   // 8 bf16 = 4 VGPRs
typedef __attribute__((ext_vector_type(4))) float f32x4;
typedef __attribute__((ext_vector_type(2))) _Float16 half2_t;

__device__ __forceinline__ short f2bf(float f) {
    union { float f; unsigned u; } v; v.f = f;
    unsigned r = v.u + 0x7FFFu + ((v.u >> 16) & 1u);   // round-to-nearest-even
    return (short)(r >> 16);
}
__device__ __forceinline__ float bf2f(short h) {
    union { unsigned u; float f; } v;
    v.u = ((unsigned)(unsigned short)h) << 16;
    return v.f;
}
__device__ __forceinline__ unsigned short f2h(float f) {
    union { _Float16 h; unsigned short u; } v;
    v.h = (_Float16)f;
    return v.u;
}
__device__ __forceinline__ half2_t u2h2(unsigned u) {
    union { unsigned u; half2_t h; } v;
    v.u = u;
    return v.h;
}

// ---------- fused: zero hist (N ints) + weight split fp32->bf16 hi/lo ----
__global__ __launch_bounds__(256) void zero_prep(
    const float* __restrict__ Wq, const float* __restrict__ Wk,
    const float* __restrict__ Wv, const float* __restrict__ Wo,
    short* __restrict__ whi, short* __restrict__ wlo,
    int* __restrict__ hist, int N)
{
    int g = blockIdx.x * 256 + threadIdx.x;
    if (g < N) hist[g] = 0;
    if (g < 65536) {
        const float* Ws[4] = {Wq, Wk, Wv, Wo};
        float f = Ws[g >> 14][g & 16383];
        short h = f2bf(f);
        short l = f2bf(f - bf2f(h));
        whi[g] = h; wlo[g] = l;
    }
}

// ---------------- fused QKV projection via split-bf16 MFMA ----------------
// Q written f16 (Qh[node*128+d]); K,V written f16 in 4-dim chunks:
// KV16[node*256 + (d>>2)*8 + (d&3)]     = K[node][d]
// KV16[node*256 + (d>>2)*8 + 4 + (d&3)] = V[node][d]
// so one uint4 (16B) = {k01,k23,v01,v23} covering dims 4c..4c+3.
__global__ __launch_bounds__(256) void qkv_mfma(
    const float* __restrict__ x,
    const short* __restrict__ whi, const short* __restrict__ wlo,
    unsigned short* __restrict__ Qh, unsigned short* __restrict__ KV16, int N)
{
    __shared__ short xs_hi[64][136];   // +8 pad: row 272 B -> 2-way LDS (free)
    __shared__ short xs_lo[64][136];

    const int tid = threadIdx.x;
    const int row0 = blockIdx.x * BM;

    #pragma unroll
    for (int i = 0; i < 8; ++i) {
        int idx = tid + 256 * i;
        int r = idx >> 5;
        int c4 = idx & 31;
        int gr = row0 + r;
        float4 val = make_float4(0.f, 0.f, 0.f, 0.f);
        if (gr < N) val = ((const float4*)(x + (size_t)gr * 128))[c4];
        short4 h, l;
        h.x = f2bf(val.x); l.x = f2bf(val.x - bf2f(h.x));
        h.y = f2bf(val.y); l.y = f2bf(val.y - bf2f(h.y));
        h.z = f2bf(val.z); l.z = f2bf(val.z - bf2f(h.z));
        h.w = f2bf(val.w); l.w = f2bf(val.w - bf2f(h.w));
        *((short4*)&xs_hi[r][c4 * 4]) = h;
        *((short4*)&xs_lo[r][c4 * 4]) = l;
    }
    __syncthreads();

    const int wid  = tid >> 6;
    const int lane = tid & 63;
    const int n16  = lane & 15;
    const int quad = lane >> 4;

    #pragma unroll 1
    for (int mat = 0; mat < 3; ++mat) {
        const short* __restrict__ WH = whi + mat * 16384;
        const short* __restrict__ WL = wlo + mat * 16384;
        const f32x4 zero = {0.f, 0.f, 0.f, 0.f};
        f32x4 acc[4][2];
        #pragma unroll
        for (int t = 0; t < 4; ++t) { acc[t][0] = zero; acc[t][1] = zero; }

        #pragma unroll
        for (int kc = 0; kc < 4; ++kc) {
            int k0 = kc * 32 + quad * 8;
            bfrag ah[4], al[4], bh[2], bl[2];
            #pragma unroll
            for (int t = 0; t < 4; ++t) {
                ah[t] = *((const bfrag*)&xs_hi[t * 16 + n16][k0]);
                al[t] = *((const bfrag*)&xs_lo[t * 16 + n16][k0]);
            }
            #pragma unroll
            for (int c = 0; c < 2; ++c) {
                int wr = (wid * 2 + c) * 16 + n16;
                bh[c] = *((const bfrag*)(WH + wr * 128 + k0));
                bl[c] = *((const bfrag*)(WL + wr * 128 + k0));
            }
            #pragma unroll
            for (int t = 0; t < 4; ++t)
                #pragma unroll
                for (int c = 0; c < 2; ++c) {
                    acc[t][c] = __builtin_amdgcn_mfma_f32_16x16x32_bf16(ah[t], bh[c], acc[t][c], 0, 0, 0);
                    acc[t][c] = __builtin_amdgcn_mfma_f32_16x16x32_bf16(al[t], bh[c], acc[t][c], 0, 0, 0);
                    acc[t][c] = __builtin_amdgcn_mfma_f32_16x16x32_bf16(ah[t], bl[c], acc[t][c], 0, 0, 0);
                }
        }
        #pragma unroll
        for (int t = 0; t < 4; ++t)
            #pragma unroll
            for (int r = 0; r < 4; ++r) {
                int grow = row0 + t * 16 + quad * 4 + r;
                if (grow < N) {
                    int c0 = (wid * 2 + 0) * 16 + n16;
                    int c1 = (wid * 2 + 1) * 16 + n16;
                    if (mat == 0) {
                        Qh[(size_t)grow * 128 + c0] = f2h(acc[t][0][r]);
                        Qh[(size_t)grow * 128 + c1] = f2h(acc[t][1][r]);
                    } else {
                        int off = (mat == 2) ? 4 : 0;
                        size_t base = (size_t)grow * 256;
                        KV16[base + (c0 >> 2) * 8 + (c0 & 3) + off] = f2h(acc[t][0][r]);
                        KV16[base + (c1 >> 2) * 8 + (c1 & 3) + off] = f2h(acc[t][1][r]);
                    }
                }
            }
    }
}

// ---------------- counting sort of edges by dst ----------------
__global__ __launch_bounds__(256) void hist_kernel(
    const int* __restrict__ ei, int* __restrict__ hist, int E)
{
    int e = blockIdx.x * blockDim.x + threadIdx.x;
    if (e < E) atomicAdd(&hist[ei[E + e]], 1);
}

#define SCAN_TPB 256
#define SCAN_EPT 4   // 1024 elements per scan block

__global__ __launch_bounds__(SCAN_TPB) void scan_partial(
    const int* __restrict__ hist, int* __restrict__ offs,
    int* __restrict__ blockSums, int N)
{
    __shared__ int sdata[SCAN_TPB];
    int b = blockIdx.x;
    int t = threadIdx.x;
    int base = b * SCAN_TPB * SCAN_EPT + t * SCAN_EPT;
    int v[SCAN_EPT];
    int tot = 0;
    #pragma unroll
    for (int j = 0; j < SCAN_EPT; ++j) {
        int idx = base + j;
        v[j] = (idx < N) ? hist[idx] : 0;
        tot += v[j];
    }
    sdata[t] = tot;
    __syncthreads();
    for (int off = 1; off < SCAN_TPB; off <<= 1) {
        int xv = (t >= off) ? sdata[t - off] : 0;
        __syncthreads();
        sdata[t] += xv;
        __syncthreads();
    }
    int run = sdata[t] - tot;
    #pragma unroll
    for (int j = 0; j < SCAN_EPT; ++j) {
        int idx = base + j;
        if (idx < N) offs[idx] = run;
        run += v[j];
    }
    if (t == SCAN_TPB - 1) blockSums[b] = sdata[t];
}

__global__ __launch_bounds__(256) void scan_blocksums(int* __restrict__ blockSums, int nb)
{
    __shared__ int sdata[256];
    int t = threadIdx.x;
    int orig = (t < nb) ? blockSums[t] : 0;
    sdata[t] = orig;
    __syncthreads();
    for (int off = 1; off < 256; off <<= 1) {
        int xv = (t >= off) ? sdata[t - off] : 0;
        __syncthreads();
        sdata[t] += xv;
        __syncthreads();
    }
    if (t < nb) blockSums[t] = sdata[t] - orig;
}

// adds block prefix; writes both offs (scatter working copy) and starts (kept)
__global__ __launch_bounds__(256) void scan_add(
    int* __restrict__ offs, int* __restrict__ starts,
    const int* __restrict__ blockSums, int N)
{
    int idx = blockIdx.x * blockDim.x + threadIdx.x;
    if (idx < N) {
        int vv = offs[idx] + blockSums[idx >> 10];
        offs[idx] = vv;
        starts[idx] = vv;
    }
}

// scatter: offs[d] consumed (becomes END offset after all increments)
__global__ __launch_bounds__(256) void scatter_kernel(
    const int* __restrict__ ei, int* __restrict__ offs,
    int* __restrict__ ssrc, int E)
{
    int e = blockIdx.x * blockDim.x + threadIdx.x;
    if (e < E) {
        int d = ei[E + e];
        int pos = atomicAdd(&offs[d], 1);
        ssrc[pos] = ei[e];
    }
}

// ---------------- per-node attention aggregation (no atomics) ----------------
// One wave per dst node, split into two 32-lane halves; each half processes
// one edge at a time (NA=4 in flight), lane covers 4 dims via one uint4
// {k01,k23,v01,v23} f16. Dot: 2x v_dot2_f32_f16; reduce: 5 ds_swizzle rounds
// within the half; sigmoid once per half; fp32 accumulate; cross-half
// combine with one shfl_xor(32) per accumulator at the end.
#define NA 4
__global__ __launch_bounds__(256) void node_agg(
    const int* __restrict__ ssrc,
    const int* __restrict__ starts,
    const int* __restrict__ endoffs,
    const unsigned short* __restrict__ Qh,
    const unsigned short* __restrict__ KV16,
    float* __restrict__ agg, int N)
{
    int node = blockIdx.x * 4 + (threadIdx.x >> 6);
    int lane = threadIdx.x & 63;
    if (node >= N) return;
    int half = lane >> 5;
    int l = lane & 31;

    int start = starts[node];
    int end = endoffs[node];
    int deg = end - start;
    int len0 = (deg + 1) >> 1;              // half 0 gets ceil, half 1 floor
    int hstart = start + half * len0;
    int hend = half ? end : (start + len0);

    uint2 qw = *((const uint2*)(Qh + (size_t)node * 128 + l * 4));
    half2_t q01 = u2h2(qw.x), q23 = u2h2(qw.y);

    float a0 = 0.f, a1 = 0.f, a2 = 0.f, a3 = 0.f;
    int iters = (len0 + NA - 1) / NA;       // len0 >= len1 always

    int base = hstart;
    for (int it = 0; it < iters; ++it, base += NA) {
        int s[NA]; bool ok[NA];
        #pragma unroll
        for (int j = 0; j < NA; ++j) {
            int idx = base + j;
            ok[j] = (idx < hend);
            idx = ok[j] ? idx : (hend - 1);   // clamp: dup load, c zeroed
            s[j] = ssrc[idx];
        }
        uint4 w[NA];
        #pragma unroll
        for (int j = 0; j < NA; ++j)
            w[j] = *((const uint4*)(KV16 + (size_t)s[j] * 256 + l * 8));
        float p[NA];
        #pragma unroll
        for (int j = 0; j < NA; ++j) {
            p[j] = __builtin_amdgcn_fdot2(u2h2(w[j].x), q01, 0.f, false);
            p[j] = __builtin_amdgcn_fdot2(u2h2(w[j].y), q23, p[j], false);
        }
        // butterfly within each 32-lane half: xor 1,2,4,8,16 (and-mask 0x1F)
        #pragma unroll
        for (int j = 0; j < NA; ++j)
            p[j] += __int_as_float(__builtin_amdgcn_ds_swizzle(__float_as_int(p[j]), 0x041F));
        #pragma unroll
        for (int j = 0; j < NA; ++j)
            p[j] += __int_as_float(__builtin_amdgcn_ds_swizzle(__float_as_int(p[j]), 0x081F));
        #pragma unroll
        for (int j = 0; j < NA; ++j)
            p[j] += __int_as_float(__builtin_amdgcn_ds_swizzle(__float_as_int(p[j]), 0x101F));
        #pragma unroll
        for (int j = 0; j < NA; ++j)
            p[j] += __int_as_float(__builtin_amdgcn_ds_swizzle(__float_as_int(p[j]), 0x201F));
        #pragma unroll
        for (int j = 0; j < NA; ++j)
            p[j] += __int_as_float(__builtin_amdgcn_ds_swizzle(__float_as_int(p[j]), 0x401F));

        #pragma unroll
        for (int j = 0; j < NA; ++j) {
            float c = 1.f / (1.f + __expf(-p[j] * 0.0883883476483184f));
            if (!ok[j]) c = 0.f;
            half2_t v01 = u2h2(w[j].z), v23 = u2h2(w[j].w);
            a0 += c * (float)v01.x; a1 += c * (float)v01.y;
            a2 += c * (float)v23.x; a3 += c * (float)v23.y;
        }
    }
    // combine halves (same dims, different edge subsets)
    a0 += __shfl_xor(a0, 32);
    a1 += __shfl_xor(a1, 32);
    a2 += __shfl_xor(a2, 32);
    a3 += __shfl_xor(a3, 32);
    if (half == 0)
        *((float4*)(agg + (size_t)node * 128 + l * 4)) = make_float4(a0, a1, a2, a3);
}

// ------- output GEMM (split-bf16 MFMA) + bias + residual + LayerNorm -------
__global__ __launch_bounds__(256) void out_ln_mfma(
    const float* __restrict__ agg,
    const short* __restrict__ whi, const short* __restrict__ wlo,  // Wo = mat 3
    const float* __restrict__ bo, const float* __restrict__ x,
    const float* __restrict__ gamma, const float* __restrict__ beta,
    float* __restrict__ out, int N)
{
    __shared__ __align__(16) char smem[64 * 136 * 2 * 2];   // 69632 B
    short (*xs_hi)[136] = (short(*)[136])smem;
    short (*xs_lo)[136] = (short(*)[136])(smem + 64 * 136 * 2);
    float (*hs)[132]    = (float(*)[132])smem;               // reused post-GEMM

    const int tid = threadIdx.x;
    const int row0 = blockIdx.x * BM;

    #pragma unroll
    for (int i = 0; i < 8; ++i) {
        int idx = tid + 256 * i;
        int r = idx >> 5;
        int c4 = idx & 31;
        int gr = row0 + r;
        float4 val = make_float4(0.f, 0.f, 0.f, 0.f);
        if (gr < N) val = ((const float4*)(agg + (size_t)gr * 128))[c4];
        short4 h, l;
        h.x = f2bf(val.x); l.x = f2bf(val.x - bf2f(h.x));
        h.y = f2bf(val.y); l.y = f2bf(val.y - bf2f(h.y));
        h.z = f2bf(val.z); l.z = f2bf(val.z - bf2f(h.z));
        h.w = f2bf(val.w); l.w = f2bf(val.w - bf2f(h.w));
        *((short4*)&xs_hi[r][c4 * 4]) = h;
        *((short4*)&xs_lo[r][c4 * 4]) = l;
    }
    __syncthreads();

    const int wid  = tid >> 6;
    const int lane = tid & 63;
    const int n16  = lane & 15;
    const int quad = lane >> 4;
    const short* __restrict__ WH = whi + 3 * 16384;
    const short* __restrict__ WL = wlo + 3 * 16384;

    const f32x4 zero = {0.f, 0.f, 0.f, 0.f};
    f32x4 acc[4][2];
    #pragma unroll
    for (int t = 0; t < 4; ++t) { acc[t][0] = zero; acc[t][1] = zero; }

    #pragma unroll
    for (int kc = 0; kc < 4; ++kc) {
        int k0 = kc * 32 + quad * 8;
        bfrag ah[4], al[4], bh[2], bl[2];
        #pragma unroll
        for (int t = 0; t < 4; ++t) {
            ah[t] = *((const bfrag*)&xs_hi[t * 16 + n16][k0]);
            al[t] = *((const bfrag*)&xs_lo[t * 16 + n16][k0]);
        }
        #pragma unroll
        for (int c = 0; c < 2; ++c) {
            int wr = (wid * 2 + c) * 16 + n16;
            bh[c] = *((const bfrag*)(WH + wr * 128 + k0));
            bl[c] = *((const bfrag*)(WL + wr * 128 + k0));
        }
        #pragma unroll
        for (int t = 0; t < 4; ++t)
            #pragma unroll
            for (int c = 0; c < 2; ++c) {
                acc[t][c] = __builtin_amdgcn_mfma_f32_16x16x32_bf16(ah[t], bh[c], acc[t][c], 0, 0, 0);
                acc[t][c] = __builtin_amdgcn_mfma_f32_16x16x32_bf16(al[t], bh[c], acc[t][c], 0, 0, 0);
                acc[t][c] = __builtin_amdgcn_mfma_f32_16x16x32_bf16(ah[t], bl[c], acc[t][c], 0, 0, 0);
            }
    }
    __syncthreads();   // all xs reads done before hs overwrite

    #pragma unroll
    for (int t = 0; t < 4; ++t)
        #pragma unroll
        for (int r = 0; r < 4; ++r) {
            hs[t * 16 + quad * 4 + r][(wid * 2 + 0) * 16 + n16] = acc[t][0][r];
            hs[t * 16 + quad * 4 + r][(wid * 2 + 1) * 16 + n16] = acc[t][1][r];
        }
    __syncthreads();

    {
        int r = tid >> 2;
        int qd = tid & 3;
        int gr = row0 + r;
        float sum = 0.f, sq = 0.f;
        #pragma unroll
        for (int c = 0; c < 32; c += 4) {
            float4 g4 = *((float4*)&hs[r][qd * 32 + c]);
            float4 b4 = *((const float4*)(bo + qd * 32 + c));
            float4 x4 = make_float4(0.f, 0.f, 0.f, 0.f);
            if (gr < N) x4 = *((const float4*)(x + (size_t)gr * 128 + qd * 32 + c));
            float4 h = make_float4(g4.x + b4.x + x4.x, g4.y + b4.y + x4.y,
                                   g4.z + b4.z + x4.z, g4.w + b4.w + x4.w);
            *((float4*)&hs[r][qd * 32 + c]) = h;
            sum += h.x + h.y + h.z + h.w;
            sq += h.x * h.x + h.y * h.y + h.z * h.z + h.w * h.w;
        }
        sum += __shfl_xor(sum, 1); sum += __shfl_xor(sum, 2);
        sq  += __shfl_xor(sq, 1);  sq  += __shfl_xor(sq, 2);
        float mu = sum * (1.f / 128.f);
        float var = sq * (1.f / 128.f) - mu * mu;
        float rs = rsqrtf(var + 1e-5f);
        if (gr < N) {
            #pragma unroll
            for (int c = 0; c < 32; c += 4) {
                float4 h = *((float4*)&hs[r][qd * 32 + c]);
                float4 g = *((const float4*)(gamma + qd * 32 + c));
                float4 b = *((const float4*)(beta + qd * 32 + c));
                float4 o = make_float4((h.x - mu) * rs * g.x + b.x,
                                       (h.y - mu) * rs * g.y + b.y,
                                       (h.z - mu) * rs * g.z + b.z,
                                       (h.w - mu) * rs * g.w + b.w);
                *((float4*)(out + (size_t)gr * 128 + qd * 32 + c)) = o;
            }
        }
    }
}

extern "C" void kernel_launch(void* const* d_in, const int* in_sizes, int n_in,
                              void* d_out, int out_size, void* d_ws, size_t ws_size,
                              hipStream_t stream) {
    const float* x     = (const float*)d_in[0];
    const int*   ei    = (const int*)d_in[1];
    const float* Wq    = (const float*)d_in[2];
    const float* Wk    = (const float*)d_in[3];
    const float* Wv    = (const float*)d_in[4];
    const float* Wo    = (const float*)d_in[5];
    const float* bo    = (const float*)d_in[6];
    const float* gamma = (const float*)d_in[7];
    const float* beta  = (const float*)d_in[8];
    const int N = in_sizes[0] / 128;
    const int E = in_sizes[1] / 2;
    const size_t ND = (size_t)N * 128;

    // workspace: Qh f16 12.8MB + KV16 f16 25.6MB + agg f32 25.6MB
    //            + hist/offs/starts + blockSums + ssrc + whi/wlo
    unsigned short* Qh   = (unsigned short*)d_ws;        // ND ushorts
    unsigned short* KV16 = Qh + ND;                      // 2*ND ushorts
    float* agg = (float*)(KV16 + 2 * ND);
    int* hist      = (int*)(agg + ND);
    int* offs      = hist + N;
    int* starts    = offs + N;
    int* blockSums = starts + N;       // 256 ints
    int* ssrc      = blockSums + 256;  // E ints
    short* whi     = (short*)(ssrc + E);        // 4*16384 shorts
    short* wlo     = whi + 4 * 16384;

    const int gzp = ((N > 65536 ? N : 65536) + 255) / 256;
    zero_prep<<<gzp, 256, 0, stream>>>(Wq, Wk, Wv, Wo, whi, wlo, hist, N);

    hist_kernel<<<(E + 255) / 256, 256, 0, stream>>>(ei, hist, E);
    const int nScanBlocks = (N + SCAN_TPB * SCAN_EPT - 1) / (SCAN_TPB * SCAN_EPT);
    scan_partial<<<nScanBlocks, SCAN_TPB, 0, stream>>>(hist, offs, blockSums, N);
    scan_blocksums<<<1, 256, 0, stream>>>(blockSums, nScanBlocks);
    scan_add<<<(N + 255) / 256, 256, 0, stream>>>(offs, starts, blockSums, N);
    scatter_kernel<<<(E + 255) / 256, 256, 0, stream>>>(ei, offs, ssrc, E);

    const int gq = (N + BM - 1) / BM;
    qkv_mfma<<<gq, 256, 0, stream>>>(x, whi, wlo, Qh, KV16, N);

    node_agg<<<(N + 3) / 4, 256, 0, stream>>>(ssrc, starts, offs, Qh, KV16, agg, N);

    out_ln_mfma<<<gq, 256, 0, stream>>>(agg, whi, wlo, bo, x, gamma, beta,
                                        (float*)d_out, N);
}

// Round 9
// 277.291 us; speedup vs baseline: 1.0231x; 1.0231x over previous
//
#include <hip/hip_runtime.h>
#include <math.h>

// N nodes (50000), E edges (600000), D=128.
// R2: f32 atomics hit TCC atomic ceiling -> counting-sort + per-node agg.
// R3: fp32 VALU GEMMs -> split-bf16 MFMA (C = xh*wh + xl*wh + xh*wl).
// R4: K/V 16-bit (halved gather bytes, 25.6 MB working set).
// R5: KV-interleaved loads, ds_swizzle reduce, masked full-width batches.
// R6: single-block scan = 103 us latency chain -> reverted to 3-kernel scan.
// R7: node_agg half-wave/f16 v_dot2 (VALU-issue-bound fix; absmax improved).
// R8: qkv_mfma exposed at ~55us, 8% MFMA/8% VALU/7.7% occ -- single
//     residency round (782 blocks @ 3/CU), zero cross-block pipelining ->
//     R9: one mat per block (3x blocks, ~3 rounds), launch_bounds(256,4).

#define BM 64

typedef __attribute__((ext_vector_type(8))) short bfrag;   // 8 bf16 = 4 VGPRs
typedef __attribute__((ext_vector_type(4))) float f32x4;
typedef __attribute__((ext_vector_type(2))) _Float16 half2_t;

__device__ __forceinline__ short f2bf(float f) {
    union { float f; unsigned u; } v; v.f = f;
    unsigned r = v.u + 0x7FFFu + ((v.u >> 16) & 1u);   // round-to-nearest-even
    return (short)(r >> 16);
}
__device__ __forceinline__ float bf2f(short h) {
    union { unsigned u; float f; } v;
    v.u = ((unsigned)(unsigned short)h) << 16;
    return v.f;
}
__device__ __forceinline__ unsigned short f2h(float f) {
    union { _Float16 h; unsigned short u; } v;
    v.h = (_Float16)f;
    return v.u;
}
__device__ __forceinline__ half2_t u2h2(unsigned u) {
    union { unsigned u; half2_t h; } v;
    v.u = u;
    return v.h;
}

// ---------- fused: zero hist (N ints) + weight split fp32->bf16 hi/lo ----
__global__ __launch_bounds__(256) void zero_prep(
    const float* __restrict__ Wq, const float* __restrict__ Wk,
    const float* __restrict__ Wv, const float* __restrict__ Wo,
    short* __restrict__ whi, short* __restrict__ wlo,
    int* __restrict__ hist, int N)
{
    int g = blockIdx.x * 256 + threadIdx.x;
    if (g < N) hist[g] = 0;
    if (g < 65536) {
        const float* Ws[4] = {Wq, Wk, Wv, Wo};
        float f = Ws[g >> 14][g & 16383];
        short h = f2bf(f);
        short l = f2bf(f - bf2f(h));
        whi[g] = h; wlo[g] = l;
    }
}

// ---------------- QKV projection via split-bf16 MFMA, ONE MAT PER BLOCK ----
// blockIdx.x = tile*3 + mat (consecutive blocks share x-tile -> L2-hot).
// Q written f16 (Qh[node*128+d]); K,V written f16 in 4-dim chunks:
// KV16[node*256 + (d>>2)*8 + (d&3)]     = K[node][d]
// KV16[node*256 + (d>>2)*8 + 4 + (d&3)] = V[node][d]
__global__ __launch_bounds__(256, 4) void qkv_mfma(
    const float* __restrict__ x,
    const short* __restrict__ whi, const short* __restrict__ wlo,
    unsigned short* __restrict__ Qh, unsigned short* __restrict__ KV16, int N)
{
    __shared__ short xs_hi[64][136];   // +8 pad: row 272 B -> 2-way LDS (free)
    __shared__ short xs_lo[64][136];

    const int tid  = threadIdx.x;
    const int mat  = blockIdx.x % 3;
    const int row0 = (blockIdx.x / 3) * BM;

    #pragma unroll
    for (int i = 0; i < 8; ++i) {
        int idx = tid + 256 * i;
        int r = idx >> 5;
        int c4 = idx & 31;
        int gr = row0 + r;
        float4 val = make_float4(0.f, 0.f, 0.f, 0.f);
        if (gr < N) val = ((const float4*)(x + (size_t)gr * 128))[c4];
        short4 h, l;
        h.x = f2bf(val.x); l.x = f2bf(val.x - bf2f(h.x));
        h.y = f2bf(val.y); l.y = f2bf(val.y - bf2f(h.y));
        h.z = f2bf(val.z); l.z = f2bf(val.z - bf2f(h.z));
        h.w = f2bf(val.w); l.w = f2bf(val.w - bf2f(h.w));
        *((short4*)&xs_hi[r][c4 * 4]) = h;
        *((short4*)&xs_lo[r][c4 * 4]) = l;
    }
    __syncthreads();

    const int wid  = tid >> 6;
    const int lane = tid & 63;
    const int n16  = lane & 15;
    const int quad = lane >> 4;

    const short* __restrict__ WH = whi + mat * 16384;
    const short* __restrict__ WL = wlo + mat * 16384;
    const f32x4 zero = {0.f, 0.f, 0.f, 0.f};
    f32x4 acc[4][2];
    #pragma unroll
    for (int t = 0; t < 4; ++t) { acc[t][0] = zero; acc[t][1] = zero; }

    #pragma unroll
    for (int kc = 0; kc < 4; ++kc) {
        int k0 = kc * 32 + quad * 8;
        bfrag ah[4], al[4], bh[2], bl[2];
        #pragma unroll
        for (int t = 0; t < 4; ++t) {
            ah[t] = *((const bfrag*)&xs_hi[t * 16 + n16][k0]);
            al[t] = *((const bfrag*)&xs_lo[t * 16 + n16][k0]);
        }
        #pragma unroll
        for (int c = 0; c < 2; ++c) {
            int wr = (wid * 2 + c) * 16 + n16;
            bh[c] = *((const bfrag*)(WH + wr * 128 + k0));
            bl[c] = *((const bfrag*)(WL + wr * 128 + k0));
        }
        #pragma unroll
        for (int t = 0; t < 4; ++t)
            #pragma unroll
            for (int c = 0; c < 2; ++c) {
                acc[t][c] = __builtin_amdgcn_mfma_f32_16x16x32_bf16(ah[t], bh[c], acc[t][c], 0, 0, 0);
                acc[t][c] = __builtin_amdgcn_mfma_f32_16x16x32_bf16(al[t], bh[c], acc[t][c], 0, 0, 0);
                acc[t][c] = __builtin_amdgcn_mfma_f32_16x16x32_bf16(ah[t], bl[c], acc[t][c], 0, 0, 0);
            }
    }

    #pragma unroll
    for (int t = 0; t < 4; ++t)
        #pragma unroll
        for (int r = 0; r < 4; ++r) {
            int grow = row0 + t * 16 + quad * 4 + r;
            if (grow < N) {
                int c0 = (wid * 2 + 0) * 16 + n16;
                int c1 = (wid * 2 + 1) * 16 + n16;
                if (mat == 0) {
                    Qh[(size_t)grow * 128 + c0] = f2h(acc[t][0][r]);
                    Qh[(size_t)grow * 128 + c1] = f2h(acc[t][1][r]);
                } else {
                    int off = (mat == 2) ? 4 : 0;
                    size_t base = (size_t)grow * 256;
                    KV16[base + (c0 >> 2) * 8 + (c0 & 3) + off] = f2h(acc[t][0][r]);
                    KV16[base + (c1 >> 2) * 8 + (c1 & 3) + off] = f2h(acc[t][1][r]);
                }
            }
        }
}

// ---------------- counting sort of edges by dst ----------------
__global__ __launch_bounds__(256) void hist_kernel(
    const int* __restrict__ ei, int* __restrict__ hist, int E)
{
    int e = blockIdx.x * blockDim.x + threadIdx.x;
    if (e < E) atomicAdd(&hist[ei[E + e]], 1);
}

#define SCAN_TPB 256
#define SCAN_EPT 4   // 1024 elements per scan block

__global__ __launch_bounds__(SCAN_TPB) void scan_partial(
    const int* __restrict__ hist, int* __restrict__ offs,
    int* __restrict__ blockSums, int N)
{
    __shared__ int sdata[SCAN_TPB];
    int b = blockIdx.x;
    int t = threadIdx.x;
    int base = b * SCAN_TPB * SCAN_EPT + t * SCAN_EPT;
    int v[SCAN_EPT];
    int tot = 0;
    #pragma unroll
    for (int j = 0; j < SCAN_EPT; ++j) {
        int idx = base + j;
        v[j] = (idx < N) ? hist[idx] : 0;
        tot += v[j];
    }
    sdata[t] = tot;
    __syncthreads();
    for (int off = 1; off < SCAN_TPB; off <<= 1) {
        int xv = (t >= off) ? sdata[t - off] : 0;
        __syncthreads();
        sdata[t] += xv;
        __syncthreads();
    }
    int run = sdata[t] - tot;
    #pragma unroll
    for (int j = 0; j < SCAN_EPT; ++j) {
        int idx = base + j;
        if (idx < N) offs[idx] = run;
        run += v[j];
    }
    if (t == SCAN_TPB - 1) blockSums[b] = sdata[t];
}

__global__ __launch_bounds__(256) void scan_blocksums(int* __restrict__ blockSums, int nb)
{
    __shared__ int sdata[256];
    int t = threadIdx.x;
    int orig = (t < nb) ? blockSums[t] : 0;
    sdata[t] = orig;
    __syncthreads();
    for (int off = 1; off < 256; off <<= 1) {
        int xv = (t >= off) ? sdata[t - off] : 0;
        __syncthreads();
        sdata[t] += xv;
        __syncthreads();
    }
    if (t < nb) blockSums[t] = sdata[t] - orig;
}

// adds block prefix; writes both offs (scatter working copy) and starts (kept)
__global__ __launch_bounds__(256) void scan_add(
    int* __restrict__ offs, int* __restrict__ starts,
    const int* __restrict__ blockSums, int N)
{
    int idx = blockIdx.x * blockDim.x + threadIdx.x;
    if (idx < N) {
        int vv = offs[idx] + blockSums[idx >> 10];
        offs[idx] = vv;
        starts[idx] = vv;
    }
}

// scatter: offs[d] consumed (becomes END offset after all increments)
__global__ __launch_bounds__(256) void scatter_kernel(
    const int* __restrict__ ei, int* __restrict__ offs,
    int* __restrict__ ssrc, int E)
{
    int e = blockIdx.x * blockDim.x + threadIdx.x;
    if (e < E) {
        int d = ei[E + e];
        int pos = atomicAdd(&offs[d], 1);
        ssrc[pos] = ei[e];
    }
}

// ---------------- per-node attention aggregation (no atomics) ----------------
// One wave per dst node, two 32-lane halves each walking half the edge list;
// lane covers 4 dims via one uint4 {k01,k23,v01,v23} f16. Dot: 2x v_dot2;
// reduce: 5 ds_swizzle rounds within the half; cross-half combine at end.
#define NA 4
__global__ __launch_bounds__(256) void node_agg(
    const int* __restrict__ ssrc,
    const int* __restrict__ starts,
    const int* __restrict__ endoffs,
    const unsigned short* __restrict__ Qh,
    const unsigned short* __restrict__ KV16,
    float* __restrict__ agg, int N)
{
    int node = blockIdx.x * 4 + (threadIdx.x >> 6);
    int lane = threadIdx.x & 63;
    if (node >= N) return;
    int half = lane >> 5;
    int l = lane & 31;

    int start = starts[node];
    int end = endoffs[node];
    int deg = end - start;
    int len0 = (deg + 1) >> 1;              // half 0 gets ceil, half 1 floor
    int hstart = start + half * len0;
    int hend = half ? end : (start + len0);

    uint2 qw = *((const uint2*)(Qh + (size_t)node * 128 + l * 4));
    half2_t q01 = u2h2(qw.x), q23 = u2h2(qw.y);

    float a0 = 0.f, a1 = 0.f, a2 = 0.f, a3 = 0.f;
    int iters = (len0 + NA - 1) / NA;       // len0 >= len1 always

    int base = hstart;
    for (int it = 0; it < iters; ++it, base += NA) {
        int s[NA]; bool ok[NA];
        #pragma unroll
        for (int j = 0; j < NA; ++j) {
            int idx = base + j;
            ok[j] = (idx < hend);
            idx = ok[j] ? idx : (hend - 1);   // clamp: dup load, c zeroed
            s[j] = ssrc[idx];
        }
        uint4 w[NA];
        #pragma unroll
        for (int j = 0; j < NA; ++j)
            w[j] = *((const uint4*)(KV16 + (size_t)s[j] * 256 + l * 8));
        float p[NA];
        #pragma unroll
        for (int j = 0; j < NA; ++j) {
            p[j] = __builtin_amdgcn_fdot2(u2h2(w[j].x), q01, 0.f, false);
            p[j] = __builtin_amdgcn_fdot2(u2h2(w[j].y), q23, p[j], false);
        }
        #pragma unroll
        for (int j = 0; j < NA; ++j)
            p[j] += __int_as_float(__builtin_amdgcn_ds_swizzle(__float_as_int(p[j]), 0x041F));
        #pragma unroll
        for (int j = 0; j < NA; ++j)
            p[j] += __int_as_float(__builtin_amdgcn_ds_swizzle(__float_as_int(p[j]), 0x081F));
        #pragma unroll
        for (int j = 0; j < NA; ++j)
            p[j] += __int_as_float(__builtin_amdgcn_ds_swizzle(__float_as_int(p[j]), 0x101F));
        #pragma unroll
        for (int j = 0; j < NA; ++j)
            p[j] += __int_as_float(__builtin_amdgcn_ds_swizzle(__float_as_int(p[j]), 0x201F));
        #pragma unroll
        for (int j = 0; j < NA; ++j)
            p[j] += __int_as_float(__builtin_amdgcn_ds_swizzle(__float_as_int(p[j]), 0x401F));

        #pragma unroll
        for (int j = 0; j < NA; ++j) {
            float c = 1.f / (1.f + __expf(-p[j] * 0.0883883476483184f));
            if (!ok[j]) c = 0.f;
            half2_t v01 = u2h2(w[j].z), v23 = u2h2(w[j].w);
            a0 += c * (float)v01.x; a1 += c * (float)v01.y;
            a2 += c * (float)v23.x; a3 += c * (float)v23.y;
        }
    }
    a0 += __shfl_xor(a0, 32);
    a1 += __shfl_xor(a1, 32);
    a2 += __shfl_xor(a2, 32);
    a3 += __shfl_xor(a3, 32);
    if (half == 0)
        *((float4*)(agg + (size_t)node * 128 + l * 4)) = make_float4(a0, a1, a2, a3);
}

// ------- output GEMM (split-bf16 MFMA) + bias + residual + LayerNorm -------
__global__ __launch_bounds__(256) void out_ln_mfma(
    const float* __restrict__ agg,
    const short* __restrict__ whi, const short* __restrict__ wlo,  // Wo = mat 3
    const float* __restrict__ bo, const float* __restrict__ x,
    const float* __restrict__ gamma, const float* __restrict__ beta,
    float* __restrict__ out, int N)
{
    __shared__ __align__(16) char smem[64 * 136 * 2 * 2];   // 69632 B
    short (*xs_hi)[136] = (short(*)[136])smem;
    short (*xs_lo)[136] = (short(*)[136])(smem + 64 * 136 * 2);
    float (*hs)[132]    = (float(*)[132])smem;               // reused post-GEMM

    const int tid = threadIdx.x;
    const int row0 = blockIdx.x * BM;

    #pragma unroll
    for (int i = 0; i < 8; ++i) {
        int idx = tid + 256 * i;
        int r = idx >> 5;
        int c4 = idx & 31;
        int gr = row0 + r;
        float4 val = make_float4(0.f, 0.f, 0.f, 0.f);
        if (gr < N) val = ((const float4*)(agg + (size_t)gr * 128))[c4];
        short4 h, l;
        h.x = f2bf(val.x); l.x = f2bf(val.x - bf2f(h.x));
        h.y = f2bf(val.y); l.y = f2bf(val.y - bf2f(h.y));
        h.z = f2bf(val.z); l.z = f2bf(val.z - bf2f(h.z));
        h.w = f2bf(val.w); l.w = f2bf(val.w - bf2f(h.w));
        *((short4*)&xs_hi[r][c4 * 4]) = h;
        *((short4*)&xs_lo[r][c4 * 4]) = l;
    }
    __syncthreads();

    const int wid  = tid >> 6;
    const int lane = tid & 63;
    const int n16  = lane & 15;
    const int quad = lane >> 4;
    const short* __restrict__ WH = whi + 3 * 16384;
    const short* __restrict__ WL = wlo + 3 * 16384;

    const f32x4 zero = {0.f, 0.f, 0.f, 0.f};
    f32x4 acc[4][2];
    #pragma unroll
    for (int t = 0; t < 4; ++t) { acc[t][0] = zero; acc[t][1] = zero; }

    #pragma unroll
    for (int kc = 0; kc < 4; ++kc) {
        int k0 = kc * 32 + quad * 8;
        bfrag ah[4], al[4], bh[2], bl[2];
        #pragma unroll
        for (int t = 0; t < 4; ++t) {
            ah[t] = *((const bfrag*)&xs_hi[t * 16 + n16][k0]);
            al[t] = *((const bfrag*)&xs_lo[t * 16 + n16][k0]);
        }
        #pragma unroll
        for (int c = 0; c < 2; ++c) {
            int wr = (wid * 2 + c) * 16 + n16;
            bh[c] = *((const bfrag*)(WH + wr * 128 + k0));
            bl[c] = *((const bfrag*)(WL + wr * 128 + k0));
        }
        #pragma unroll
        for (int t = 0; t < 4; ++t)
            #pragma unroll
            for (int c = 0; c < 2; ++c) {
                acc[t][c] = __builtin_amdgcn_mfma_f32_16x16x32_bf16(ah[t], bh[c], acc[t][c], 0, 0, 0);
                acc[t][c] = __builtin_amdgcn_mfma_f32_16x16x32_bf16(al[t], bh[c], acc[t][c], 0, 0, 0);
                acc[t][c] = __builtin_amdgcn_mfma_f32_16x16x32_bf16(ah[t], bl[c], acc[t][c], 0, 0, 0);
            }
    }
    __syncthreads();   // all xs reads done before hs overwrite

    #pragma unroll
    for (int t = 0; t < 4; ++t)
        #pragma unroll
        for (int r = 0; r < 4; ++r) {
            hs[t * 16 + quad * 4 + r][(wid * 2 + 0) * 16 + n16] = acc[t][0][r];
            hs[t * 16 + quad * 4 + r][(wid * 2 + 1) * 16 + n16] = acc[t][1][r];
        }
    __syncthreads();

    {
        int r = tid >> 2;
        int qd = tid & 3;
        int gr = row0 + r;
        float sum = 0.f, sq = 0.f;
        #pragma unroll
        for (int c = 0; c < 32; c += 4) {
            float4 g4 = *((float4*)&hs[r][qd * 32 + c]);
            float4 b4 = *((const float4*)(bo + qd * 32 + c));
            float4 x4 = make_float4(0.f, 0.f, 0.f, 0.f);
            if (gr < N) x4 = *((const float4*)(x + (size_t)gr * 128 + qd * 32 + c));
            float4 h = make_float4(g4.x + b4.x + x4.x, g4.y + b4.y + x4.y,
                                   g4.z + b4.z + x4.z, g4.w + b4.w + x4.w);
            *((float4*)&hs[r][qd * 32 + c]) = h;
            sum += h.x + h.y + h.z + h.w;
            sq += h.x * h.x + h.y * h.y + h.z * h.z + h.w * h.w;
        }
        sum += __shfl_xor(sum, 1); sum += __shfl_xor(sum, 2);
        sq  += __shfl_xor(sq, 1);  sq  += __shfl_xor(sq, 2);
        float mu = sum * (1.f / 128.f);
        float var = sq * (1.f / 128.f) - mu * mu;
        float rs = rsqrtf(var + 1e-5f);
        if (gr < N) {
            #pragma unroll
            for (int c = 0; c < 32; c += 4) {
                float4 h = *((float4*)&hs[r][qd * 32 + c]);
                float4 g = *((const float4*)(gamma + qd * 32 + c));
                float4 b = *((const float4*)(beta + qd * 32 + c));
                float4 o = make_float4((h.x - mu) * rs * g.x + b.x,
                                       (h.y - mu) * rs * g.y + b.y,
                                       (h.z - mu) * rs * g.z + b.z,
                                       (h.w - mu) * rs * g.w + b.w);
                *((float4*)(out + (size_t)gr * 128 + qd * 32 + c)) = o;
            }
        }
    }
}

extern "C" void kernel_launch(void* const* d_in, const int* in_sizes, int n_in,
                              void* d_out, int out_size, void* d_ws, size_t ws_size,
                              hipStream_t stream) {
    const float* x     = (const float*)d_in[0];
    const int*   ei    = (const int*)d_in[1];
    const float* Wq    = (const float*)d_in[2];
    const float* Wk    = (const float*)d_in[3];
    const float* Wv    = (const float*)d_in[4];
    const float* Wo    = (const float*)d_in[5];
    const float* bo    = (const float*)d_in[6];
    const float* gamma = (const float*)d_in[7];
    const float* beta  = (const float*)d_in[8];
    const int N = in_sizes[0] / 128;
    const int E = in_sizes[1] / 2;
    const size_t ND = (size_t)N * 128;

    // workspace: Qh f16 12.8MB + KV16 f16 25.6MB + agg f32 25.6MB
    //            + hist/offs/starts + blockSums + ssrc + whi/wlo
    unsigned short* Qh   = (unsigned short*)d_ws;        // ND ushorts
    unsigned short* KV16 = Qh + ND;                      // 2*ND ushorts
    float* agg = (float*)(KV16 + 2 * ND);
    int* hist      = (int*)(agg + ND);
    int* offs      = hist + N;
    int* starts    = offs + N;
    int* blockSums = starts + N;       // 256 ints
    int* ssrc      = blockSums + 256;  // E ints
    short* whi     = (short*)(ssrc + E);        // 4*16384 shorts
    short* wlo     = whi + 4 * 16384;

    const int gzp = ((N > 65536 ? N : 65536) + 255) / 256;
    zero_prep<<<gzp, 256, 0, stream>>>(Wq, Wk, Wv, Wo, whi, wlo, hist, N);

    hist_kernel<<<(E + 255) / 256, 256, 0, stream>>>(ei, hist, E);
    const int nScanBlocks = (N + SCAN_TPB * SCAN_EPT - 1) / (SCAN_TPB * SCAN_EPT);
    scan_partial<<<nScanBlocks, SCAN_TPB, 0, stream>>>(hist, offs, blockSums, N);
    scan_blocksums<<<1, 256, 0, stream>>>(blockSums, nScanBlocks);
    scan_add<<<(N + 255) / 256, 256, 0, stream>>>(offs, starts, blockSums, N);
    scatter_kernel<<<(E + 255) / 256, 256, 0, stream>>>(ei, offs, ssrc, E);

    const int gq = (N + BM - 1) / BM;
    qkv_mfma<<<gq * 3, 256, 0, stream>>>(x, whi, wlo, Qh, KV16, N);

    node_agg<<<(N + 3) / 4, 256, 0, stream>>>(ssrc, starts, offs, Qh, KV16, agg, N);

    out_ln_mfma<<<gq, 256, 0, stream>>>(agg, whi, wlo, bo, x, gamma, beta,
                                        (float*)d_out, N);
}